// Round 9
// baseline (159.806 us; speedup 1.0000x reference)
//
#include <hip/hip_runtime.h>
#include <hip/hip_bf16.h>

#define B_NUM 2
#define S_LEN 2048
#define E_DIM 1024
#define H_NUM 16
#define D_DIM 64
#define QKV_LD 3072
// 1/sqrt(64) * log2(e): folded so softmax exp is a bare v_exp_f32 (exp2)
#define QSCALE_LOG2E 0.18033688011112042f

typedef __attribute__((ext_vector_type(8))) short bf16x8;
typedef __attribute__((ext_vector_type(8))) unsigned short u16x8;
typedef __attribute__((ext_vector_type(4))) unsigned short u16x4;
typedef __attribute__((ext_vector_type(4))) float f32x4;
typedef __attribute__((ext_vector_type(16))) float f32x16;
typedef __attribute__((ext_vector_type(2))) int i32x2;

static __device__ __forceinline__ unsigned short f2bf(float f) {
    union { float f; unsigned int u; } v; v.f = f;
    unsigned int r = v.u + 0x7fffu + ((v.u >> 16) & 1u);   // RNE
    return (unsigned short)(r >> 16);
}

static __device__ __forceinline__ unsigned cvtpk_bf16(float lo, float hi) {
    unsigned r;
    asm("v_cvt_pk_bf16_f32 %0, %1, %2" : "=v"(r) : "v"(lo), "v"(hi));
    return r;
}

// async global->LDS, 16B per lane; LDS dest = uniform base + lane*16
static __device__ __forceinline__ void gload16(const void* gsrc, void* ldst) {
    __builtin_amdgcn_global_load_lds(
        (const __attribute__((address_space(1))) unsigned int*)gsrc,
        (__attribute__((address_space(3))) unsigned int*)ldst, 16, 0, 0);
}

// ---------------------------------------------------------------------------
// fp32 -> bf16 bulk convert
// ---------------------------------------------------------------------------
__global__ __launch_bounds__(256)
void cvt_f32_bf16(const float* __restrict__ in, unsigned short* __restrict__ outp, int n4) {
    int i = blockIdx.x * blockDim.x + threadIdx.x;
    if (i < n4) {
        float4 f = ((const float4*)in)[i];
        u16x4 o = { f2bf(f.x), f2bf(f.y), f2bf(f.z), f2bf(f.w) };
        ((u16x4*)outp)[i] = o;
    }
}

// ---------------------------------------------------------------------------
// 128x128 bf16 MFMA GEMM, BK=64, 4 waves. global_load_lds staging with
// pre-swizzled global source. (proven rounds 4-8)
// ---------------------------------------------------------------------------
template <bool OUT_BF16, bool QSCALE>
__global__ __launch_bounds__(256)
void gemm_bt_mfma128(const unsigned short* __restrict__ A,
                     const unsigned short* __restrict__ Bw,
                     void* __restrict__ Cv, int M, int N, int K) {
    __shared__ unsigned short As[128 * 64];
    __shared__ unsigned short Bs[128 * 64];
    char* const AsB = (char*)As;
    char* const BsB = (char*)Bs;
    const int tid  = threadIdx.x;
    const int lane = tid & 63;
    const int w    = tid >> 6;
    const int lg   = lane >> 4;
    const int lq   = lane & 15;
    const int bm = blockIdx.y * 128;
    const int bn = blockIdx.x * 128;
    const int wr = (w >> 1) * 64;
    const int wc = (w & 1) * 64;
    const int lrow8 = lane >> 3;
    const int gblk  = (lane & 7) ^ lrow8;

    f32x4 acc[4][4];
#pragma unroll
    for (int i = 0; i < 4; ++i)
#pragma unroll
        for (int j = 0; j < 4; ++j) acc[i][j] = (f32x4){0.f, 0.f, 0.f, 0.f};

    for (int k0 = 0; k0 < K; k0 += 64) {
        __syncthreads();
#pragma unroll
        for (int t = 0; t < 4; ++t) {
            const int c = w * 4 + t;
            const int row = c * 8 + lrow8;
            gload16(A + (size_t)(bm + row) * K + k0 + gblk * 8, AsB + c * 1024);
            gload16(Bw + (size_t)(bn + row) * K + k0 + gblk * 8, BsB + c * 1024);
        }
        __syncthreads();

        bf16x8 af[4][2], bfr[4][2];
#pragma unroll
        for (int rt = 0; rt < 4; ++rt) {
            const int row = wr + rt * 16 + lq;
            const int sz = (row & 7) << 4;
            af[rt][0] = *(const bf16x8*)(AsB + row * 128 + ((lg * 16)      ^ sz));
            af[rt][1] = *(const bf16x8*)(AsB + row * 128 + ((64 + lg * 16) ^ sz));
        }
#pragma unroll
        for (int ct = 0; ct < 4; ++ct) {
            const int row = wc + ct * 16 + lq;
            const int sz = (row & 7) << 4;
            bfr[ct][0] = *(const bf16x8*)(BsB + row * 128 + ((lg * 16)      ^ sz));
            bfr[ct][1] = *(const bf16x8*)(BsB + row * 128 + ((64 + lg * 16) ^ sz));
        }
#pragma unroll
        for (int rt = 0; rt < 4; ++rt)
#pragma unroll
            for (int ct = 0; ct < 4; ++ct) {
                acc[rt][ct] = __builtin_amdgcn_mfma_f32_16x16x32_bf16(af[rt][0], bfr[ct][0], acc[rt][ct], 0, 0, 0);
                acc[rt][ct] = __builtin_amdgcn_mfma_f32_16x16x32_bf16(af[rt][1], bfr[ct][1], acc[rt][ct], 0, 0, 0);
            }
    }

#pragma unroll
    for (int rt = 0; rt < 4; ++rt)
#pragma unroll
        for (int ct = 0; ct < 4; ++ct) {
            const int row = bm + wr + rt * 16 + lg * 4;
            const int col = bn + wc + ct * 16 + lq;
            float scale = 1.f;
            if constexpr (QSCALE) scale = ((col % 192) < 64) ? QSCALE_LOG2E : 1.f;
#pragma unroll
            for (int r = 0; r < 4; ++r) {
                float vv = acc[rt][ct][r] * scale;
                if constexpr (OUT_BF16)
                    ((unsigned short*)Cv)[(size_t)(row + r) * N + col] = f2bf(vv);
                else
                    ((float*)Cv)[(size_t)(row + r) * N + col] = vv;
            }
        }
}

// ---------------------------------------------------------------------------
// 64x64 bf16 MFMA GEMM (known-good; output projection)
// ---------------------------------------------------------------------------
template <bool OUT_BF16, bool QSCALE>
__global__ __launch_bounds__(256)
void gemm_bt_mfma(const unsigned short* __restrict__ A,
                  const unsigned short* __restrict__ Bw,
                  void* __restrict__ Cv, int M, int N, int K) {
    __shared__ unsigned short As[64 * 64];
    __shared__ unsigned short Bs[64 * 64];
    char* const AsB = (char*)As;
    char* const BsB = (char*)Bs;
    const int tid  = threadIdx.x;
    const int lane = tid & 63;
    const int w    = tid >> 6;
    const int lg   = lane >> 4;
    const int lq   = lane & 15;
    const int bm = blockIdx.y * 64;
    const int bn = blockIdx.x * 64;
    const int wr = (w >> 1) * 32;
    const int wc = (w & 1) * 32;
    const int sr = tid >> 2;
    const int sc = (tid & 3) * 16;
    const int swzS = (sr & 7) << 4;

    f32x4 acc[2][2];
#pragma unroll
    for (int i = 0; i < 2; ++i)
#pragma unroll
        for (int j = 0; j < 2; ++j) acc[i][j] = (f32x4){0.f, 0.f, 0.f, 0.f};

    const unsigned short* ap = A  + (size_t)(bm + sr) * K + sc;
    const unsigned short* bp = Bw + (size_t)(bn + sr) * K + sc;

    for (int k0 = 0; k0 < K; k0 += 64) {
        __syncthreads();
        u16x8 av0 = *(const u16x8*)(ap + k0);
        u16x8 av1 = *(const u16x8*)(ap + k0 + 8);
        u16x8 bv0 = *(const u16x8*)(bp + k0);
        u16x8 bv1 = *(const u16x8*)(bp + k0 + 8);
        *(u16x8*)(AsB + sr * 128 + ((sc * 2)      ^ swzS)) = av0;
        *(u16x8*)(AsB + sr * 128 + ((sc * 2 + 16) ^ swzS)) = av1;
        *(u16x8*)(BsB + sr * 128 + ((sc * 2)      ^ swzS)) = bv0;
        *(u16x8*)(BsB + sr * 128 + ((sc * 2 + 16) ^ swzS)) = bv1;
        __syncthreads();

        bf16x8 af[2][2], bfr[2][2];
#pragma unroll
        for (int rt = 0; rt < 2; ++rt) {
            const int row = wr + rt * 16 + lq;
            const int sz = (row & 7) << 4;
            af[rt][0] = *(const bf16x8*)(AsB + row * 128 + ((lg * 16)      ^ sz));
            af[rt][1] = *(const bf16x8*)(AsB + row * 128 + ((64 + lg * 16) ^ sz));
        }
#pragma unroll
        for (int ct = 0; ct < 2; ++ct) {
            const int row = wc + ct * 16 + lq;
            const int sz = (row & 7) << 4;
            bfr[ct][0] = *(const bf16x8*)(BsB + row * 128 + ((lg * 16)      ^ sz));
            bfr[ct][1] = *(const bf16x8*)(BsB + row * 128 + ((64 + lg * 16) ^ sz));
        }
#pragma unroll
        for (int rt = 0; rt < 2; ++rt)
#pragma unroll
            for (int ct = 0; ct < 2; ++ct) {
                acc[rt][ct] = __builtin_amdgcn_mfma_f32_16x16x32_bf16(af[rt][0], bfr[ct][0], acc[rt][ct], 0, 0, 0);
                acc[rt][ct] = __builtin_amdgcn_mfma_f32_16x16x32_bf16(af[rt][1], bfr[ct][1], acc[rt][ct], 0, 0, 0);
            }
    }

#pragma unroll
    for (int rt = 0; rt < 2; ++rt)
#pragma unroll
        for (int ct = 0; ct < 2; ++ct) {
            const int row = bm + wr + rt * 16 + lg * 4;
            const int col = bn + wc + ct * 16 + lq;
            float scale = 1.f;
            if constexpr (QSCALE) scale = ((col % 192) < 64) ? QSCALE_LOG2E : 1.f;
#pragma unroll
            for (int r = 0; r < 4; ++r) {
                float vv = acc[rt][ct][r] * scale;
                if constexpr (OUT_BF16)
                    ((unsigned short*)Cv)[(size_t)(row + r) * N + col] = f2bf(vv);
                else
                    ((float*)Cv)[(size_t)(row + r) * N + col] = vv;
            }
        }
}

// ---------------------------------------------------------------------------
// Flash attention v9: v8 (wave-split operand reuse, no-max softmax, XCD
// remap) with 128-KEY TILES — rounds 32->16, one barrier per 128 keys.
// The 128-key tile is stored as two 64-key sub-buffers (u = 0,1), each
// identical in layout to v8's tile, processed sequentially per round.
// LDS: K 2x16KB + V 2x16KB + bias 8KB = 74KB -> 2 blocks/CU (= grid/CU).
// ---------------------------------------------------------------------------
__global__ __launch_bounds__(256)
void attn_v9(const unsigned short* __restrict__ qkv, const int* __restrict__ mask,
             unsigned short* __restrict__ vout) {
    __shared__ __align__(16) char poolK[2][2][8192];   // [dbuf][u]
    __shared__ __align__(16) char poolV[2][2][8192];
    __shared__ __align__(16) float BiasF[S_LEN];
    __shared__ float RsM[2][2][32];

    const int tid  = threadIdx.x;
    const int lane = tid & 63;
    const int w    = tid >> 6;
    const int ln   = lane & 31;
    const int hi   = lane >> 5;
    const int qh   = w >> 1;      // q-half (64 q)
    const int kh   = w & 1;       // key-half (32 keys per 64-key subtile)

    // XCD-aware remap: one (b,h)'s 16 q-blocks share an XCD.
    const int d0  = blockIdx.x + 16 * blockIdx.y + 256 * blockIdx.z;
    const int lin = (d0 & 7) * 64 + (d0 >> 3);
    const int q0 = (lin & 15) * 128;
    const int h  = (lin >> 4) & 15;
    const int b  = lin >> 8;
    const unsigned short* const kv =
        qkv + (size_t)b * S_LEN * QKV_LD + (size_t)h * (3 * D_DIM);

    // ---- stage full bias row once ----
    {
        const int4* mr = (const int4*)(mask + (size_t)b * S_LEN);
        int4 m0 = mr[tid * 2];
        int4 m1 = mr[tid * 2 + 1];
        float4 f0 = { m0.x ? 0.f : -30000.f, m0.y ? 0.f : -30000.f,
                      m0.z ? 0.f : -30000.f, m0.w ? 0.f : -30000.f };
        float4 f1 = { m1.x ? 0.f : -30000.f, m1.y ? 0.f : -30000.f,
                      m1.z ? 0.f : -30000.f, m1.w ? 0.f : -30000.f };
        ((float4*)BiasF)[tid * 2]     = f0;
        ((float4*)BiasF)[tid * 2 + 1] = f1;
    }

    // Q B-frags for both q-subtiles (pre-scaled by 0.125*log2e)
    bf16x8 qf[2][4];
#pragma unroll
    for (int qs = 0; qs < 2; ++qs) {
        const unsigned short* qp = kv + (size_t)(q0 + qh * 64 + qs * 32 + ln) * QKV_LD + hi * 8;
#pragma unroll
        for (int kk = 0; kk < 4; ++kk)
            qf[qs][kk] = *(const bf16x8*)(qp + kk * 16);
    }

    const int lrow8 = lane >> 3;
    const int gblk  = (lane & 7) ^ lrow8;   // pre-swizzled 16B block for K stage
    const int vkb = (tid & 15) * 4;         // V staging key base
    const int vdb = (tid >> 4) * 4;         // V staging d base

    // ---- stage tile 0 (both 64-key subtiles) into dbuf 0 ----
    {
#pragma unroll
        for (int t = 0; t < 4; ++t) {
            const int c = w * 4 + t;        // 0..15
            const int u = c >> 3, c8 = c & 7;
            gload16(kv + (size_t)(u * 64 + c8 * 8 + lrow8) * QKV_LD + D_DIM + gblk * 8,
                    poolK[0][u] + c8 * 1024);
        }
#pragma unroll
        for (int u = 0; u < 2; ++u) {
            u16x4 vr[4];
#pragma unroll
            for (int i = 0; i < 4; ++i)
                vr[i] = *(const u16x4*)(kv + (size_t)(u * 64 + vkb + i) * QKV_LD + 2 * D_DIM + vdb);
#pragma unroll
            for (int j = 0; j < 4; ++j) {
                u16x4 o = { vr[0][j], vr[1][j], vr[2][j], vr[3][j] };
                const int row = vdb + j;
                *(u16x4*)(poolV[0][u] + row * 128 + ((vkb * 2) ^ ((row & 7) << 4))) = o;
            }
        }
    }
    __syncthreads();

    f32x16 accO[2][2];   // [dt][qs]
#pragma unroll
    for (int dt = 0; dt < 2; ++dt)
#pragma unroll
        for (int qs = 0; qs < 2; ++qs)
#pragma unroll
            for (int r = 0; r < 16; ++r) accO[dt][qs][r] = 0.f;
    f32x4 rsv[2] = {(f32x4){0.f, 0.f, 0.f, 0.f}, (f32x4){0.f, 0.f, 0.f, 0.f}};

    const int NT = S_LEN / 128;   // 16
    const int krow = kh * 32 + ln;
    const int kswz = (ln & 7) << 4;
    for (int it = 0; it < NT; ++it) {
        const int cur = it & 1;
        const int kv0 = it * 128;
        const bool pf = (it + 1 < NT);

        // ---- prefetch tile it+1 (issue only): V regs first, K gloads ----
        u16x4 vrn[2][4];
        if (pf) {
            const int kvn = kv0 + 128;
#pragma unroll
            for (int u = 0; u < 2; ++u)
#pragma unroll
                for (int i = 0; i < 4; ++i)
                    vrn[u][i] = *(const u16x4*)(kv + (size_t)(kvn + u * 64 + vkb + i) * QKV_LD + 2 * D_DIM + vdb);
#pragma unroll
            for (int t = 0; t < 4; ++t) {
                const int c = w * 4 + t;
                const int u = c >> 3, c8 = c & 7;
                gload16(kv + (size_t)(kvn + u * 64 + c8 * 8 + lrow8) * QKV_LD + D_DIM + gblk * 8,
                        poolK[cur ^ 1][u] + c8 * 1024);
            }
        }

        // ---- two 64-key subtiles, sequential (keeps s liveness at 32) ----
#pragma unroll
        for (int u = 0; u < 2; ++u) {
            const char* const KsC = poolK[cur][u];
            const char* const VtC = poolV[cur][u];

            bf16x8 kf[4];
#pragma unroll
            for (int kk = 0; kk < 4; ++kk)
                kf[kk] = *(const bf16x8*)(KsC + krow * 128 + (((kk * 16 + hi * 8) * 2) ^ kswz));

            f32x16 s[2];
#pragma unroll
            for (int m = 0; m < 4; ++m) {
                f32x4 b4 = *(const f32x4*)(&BiasF[kv0 + u * 64 + kh * 32 + m * 8 + hi * 4]);
#pragma unroll
                for (int i = 0; i < 4; ++i) { s[0][m * 4 + i] = b4[i]; s[1][m * 4 + i] = b4[i]; }
            }

            __builtin_amdgcn_s_setprio(1);
#pragma unroll
            for (int kk = 0; kk < 4; ++kk) {
                s[0] = __builtin_amdgcn_mfma_f32_32x32x16_bf16(kf[kk], qf[0][kk], s[0], 0, 0, 0);
                s[1] = __builtin_amdgcn_mfma_f32_32x32x16_bf16(kf[kk], qf[1][kk], s[1], 0, 0, 0);
            }
            __builtin_amdgcn_s_setprio(0);

#pragma unroll
            for (int qs = 0; qs < 2; ++qs)
#pragma unroll
                for (int r = 0; r < 16; ++r) {
                    float p = __builtin_amdgcn_exp2f(s[qs][r]);
                    s[qs][r] = p;
                    rsv[qs][r & 3] += p;
                }

            bf16x8 pb[2][2];
#pragma unroll
            for (int qs = 0; qs < 2; ++qs) {
                unsigned wA[4], wB[4];
#pragma unroll
                for (int m = 0; m < 4; ++m) {
                    wA[m] = cvtpk_bf16(s[qs][4 * m + 0], s[qs][4 * m + 1]);
                    wB[m] = cvtpk_bf16(s[qs][4 * m + 2], s[qs][4 * m + 3]);
                }
#pragma unroll
                for (int t = 0; t < 2; ++t) {
                    i32x2 ra = __builtin_amdgcn_permlane32_swap((int)wA[2 * t], (int)wA[2 * t + 1], false, false);
                    i32x2 rb = __builtin_amdgcn_permlane32_swap((int)wB[2 * t], (int)wB[2 * t + 1], false, false);
                    union { unsigned u[4]; bf16x8 v; } uu;
                    uu.u[0] = (unsigned)ra[0];
                    uu.u[1] = (unsigned)rb[0];
                    uu.u[2] = (unsigned)ra[1];
                    uu.u[3] = (unsigned)rb[1];
                    pb[qs][t] = uu.v;
                }
            }

            __builtin_amdgcn_s_setprio(1);
#pragma unroll
            for (int dt = 0; dt < 2; ++dt) {
                const int drow = dt * 32 + ln;
                const int swz = (ln & 7) << 4;
#pragma unroll
                for (int t = 0; t < 2; ++t) {
                    const int n = 2 * kh + t;
                    bf16x8 va = *(const bf16x8*)(VtC + drow * 128 + (((n * 16 + hi * 8) * 2) ^ swz));
                    accO[dt][0] = __builtin_amdgcn_mfma_f32_32x32x16_bf16(va, pb[0][t], accO[dt][0], 0, 0, 0);
                    accO[dt][1] = __builtin_amdgcn_mfma_f32_32x32x16_bf16(va, pb[1][t], accO[dt][1], 0, 0, 0);
                }
            }
            __builtin_amdgcn_s_setprio(0);
        }

        // ---- complete V prefetch: regs -> LDS (transposed, swizzled) ----
        if (pf) {
#pragma unroll
            for (int u = 0; u < 2; ++u)
#pragma unroll
                for (int j = 0; j < 4; ++j) {
                    u16x4 o = { vrn[u][0][j], vrn[u][1][j], vrn[u][2][j], vrn[u][3][j] };
                    const int row = vdb + j;
                    *(u16x4*)(poolV[cur ^ 1][u] + row * 128 + ((vkb * 2) ^ ((row & 7) << 4))) = o;
                }
        }
        __syncthreads();   // drains gload_lds + ds_writes; flips buffers
    }

    // ---- per-wave row-sum: in-lane + hi-partner reduce ----
    float rs[2];
#pragma unroll
    for (int qs = 0; qs < 2; ++qs) {
        float t = rsv[qs][0] + rsv[qs][1] + rsv[qs][2] + rsv[qs][3];
        i32x2 rr = __builtin_amdgcn_permlane32_swap(__float_as_int(t), __float_as_int(t), false, false);
        rs[qs] = __int_as_float(rr[0]) + __int_as_float(rr[1]);
    }

    // ---- merge key-half partials across wave pairs (exact addition) ----
    __syncthreads();                      // all K/V buffer use done; pool free
    char* const mergebase = (char*)poolK; // 64KB scratch, use [qh] 16KB regions
    const int lswz = (lane & 7) << 4;
    if (kh == 1) {                        // odd waves: publish partials
        char* const reg = mergebase + qh * 16384;
#pragma unroll
        for (int qs = 0; qs < 2; ++qs) {
#pragma unroll
            for (int dt = 0; dt < 2; ++dt)
#pragma unroll
                for (int r4 = 0; r4 < 4; ++r4) {
                    f32x4 v = { accO[dt][qs][4 * r4 + 0], accO[dt][qs][4 * r4 + 1],
                                accO[dt][qs][4 * r4 + 2], accO[dt][qs][4 * r4 + 3] };
                    *(f32x4*)(reg + lane * 256 + ((qs * 128 + dt * 64 + r4 * 16) ^ lswz)) = v;
                }
            if (hi == 0) RsM[qh][qs][ln] = rs[qs];
        }
    }
    __syncthreads();
    if (kh == 0) {                        // even waves: combine + store
        const char* const reg = mergebase + qh * 16384;
#pragma unroll
        for (int qs = 0; qs < 2; ++qs) {
            const float inv = 1.f / (rs[qs] + RsM[qh][qs][ln]);
            unsigned short* op = vout +
                (size_t)(b * S_LEN + q0 + qh * 64 + qs * 32 + ln) * E_DIM + h * D_DIM;
#pragma unroll
            for (int dt = 0; dt < 2; ++dt)
#pragma unroll
                for (int m = 0; m < 4; ++m) {
                    f32x4 part = *(const f32x4*)(reg + lane * 256 + ((qs * 128 + dt * 64 + m * 16) ^ lswz));
                    u16x4 o;
#pragma unroll
                    for (int i = 0; i < 4; ++i)
                        o[i] = f2bf((accO[dt][qs][4 * m + i] + part[i]) * inv);
                    *(u16x4*)(op + dt * 32 + m * 8 + hi * 4) = o;
                }
        }
    }
}

// ---------------------------------------------------------------------------
extern "C" void kernel_launch(void* const* d_in, const int* in_sizes, int n_in,
                              void* d_out, int out_size, void* d_ws, size_t ws_size,
                              hipStream_t stream) {
    const float* x      = (const float*)d_in[0];
    const int*   mask   = (const int*)d_in[1];
    const float* w_qkv  = (const float*)d_in[2];
    const float* w_o    = (const float*)d_in[3];
    float*       out    = (float*)d_out;

    const int M = B_NUM * S_LEN;     // 4096
    unsigned short* qkvb = (unsigned short*)d_ws;                    // M x 3E
    unsigned short* vbuf = qkvb + (size_t)M * 3 * E_DIM;             // M x E
    unsigned short* xb   = vbuf + (size_t)M * E_DIM;                 // M x E
    unsigned short* wqb  = xb   + (size_t)M * E_DIM;                 // 3E x E
    unsigned short* wob  = wqb  + (size_t)3 * E_DIM * E_DIM;         // E x E

    dim3 blk(256);
    {
        int n4;
        n4 = M * E_DIM / 4;
        cvt_f32_bf16<<<dim3((n4 + 255) / 256), blk, 0, stream>>>(x, xb, n4);
        n4 = 3 * E_DIM * E_DIM / 4;
        cvt_f32_bf16<<<dim3((n4 + 255) / 256), blk, 0, stream>>>(w_qkv, wqb, n4);
        n4 = E_DIM * E_DIM / 4;
        cvt_f32_bf16<<<dim3((n4 + 255) / 256), blk, 0, stream>>>(w_o, wob, n4);
    }

    // QKV projection (q columns pre-scaled by 0.125*log2e), bf16 out
    gemm_bt_mfma128<true, true><<<dim3(3 * E_DIM / 128, M / 128), blk, 0, stream>>>(
        xb, wqb, qkvb, M, 3 * E_DIM, E_DIM);

    // flash attention v9 (128-key tiles, wave-split reuse)
    attn_v9<<<dim3(S_LEN / 128, H_NUM, B_NUM), blk, 0, stream>>>(qkvb, mask, vbuf);

    // output projection, fp32 out
    gemm_bt_mfma<false, false><<<dim3(E_DIM / 64, M / 64), blk, 0, stream>>>(
        vbuf, wob, out, M, E_DIM, E_DIM);
}

// Round 10
// 128.815 us; speedup vs baseline: 1.2406x; 1.2406x over previous
//
#include <hip/hip_runtime.h>
#include <hip/hip_bf16.h>

#define B_NUM 2
#define S_LEN 2048
#define E_DIM 1024
#define H_NUM 16
#define D_DIM 64
#define QKV_LD 3072
// 1/sqrt(64) * log2(e): folded so softmax exp is a bare v_exp_f32 (exp2)
#define QSCALE_LOG2E 0.18033688011112042f

typedef __attribute__((ext_vector_type(8))) short bf16x8;
typedef __attribute__((ext_vector_type(8))) unsigned short u16x8;
typedef __attribute__((ext_vector_type(4))) unsigned short u16x4;
typedef __attribute__((ext_vector_type(4))) float f32x4;
typedef __attribute__((ext_vector_type(16))) float f32x16;
typedef __attribute__((ext_vector_type(2))) int i32x2;

static __device__ __forceinline__ unsigned short f2bf(float f) {
    union { float f; unsigned int u; } v; v.f = f;
    unsigned int r = v.u + 0x7fffu + ((v.u >> 16) & 1u);   // RNE
    return (unsigned short)(r >> 16);
}

static __device__ __forceinline__ unsigned cvtpk_bf16(float lo, float hi) {
    unsigned r;
    asm("v_cvt_pk_bf16_f32 %0, %1, %2" : "=v"(r) : "v"(lo), "v"(hi));
    return r;
}

// async global->LDS, 16B per lane; LDS dest = uniform base + lane*16
static __device__ __forceinline__ void gload16(const void* gsrc, void* ldst) {
    __builtin_amdgcn_global_load_lds(
        (const __attribute__((address_space(1))) unsigned int*)gsrc,
        (__attribute__((address_space(3))) unsigned int*)ldst, 16, 0, 0);
}

// ---------------------------------------------------------------------------
// fp32 -> bf16 bulk convert
// ---------------------------------------------------------------------------
__global__ __launch_bounds__(256)
void cvt_f32_bf16(const float* __restrict__ in, unsigned short* __restrict__ outp, int n4) {
    int i = blockIdx.x * blockDim.x + threadIdx.x;
    if (i < n4) {
        float4 f = ((const float4*)in)[i];
        u16x4 o = { f2bf(f.x), f2bf(f.y), f2bf(f.z), f2bf(f.w) };
        ((u16x4*)outp)[i] = o;
    }
}

// ---------------------------------------------------------------------------
// 128x128 bf16 MFMA GEMM, BK=64, 4 waves. global_load_lds staging with
// pre-swizzled global source. (proven rounds 4-9)
// ---------------------------------------------------------------------------
template <bool OUT_BF16, bool QSCALE>
__global__ __launch_bounds__(256)
void gemm_bt_mfma128(const unsigned short* __restrict__ A,
                     const unsigned short* __restrict__ Bw,
                     void* __restrict__ Cv, int M, int N, int K) {
    __shared__ unsigned short As[128 * 64];
    __shared__ unsigned short Bs[128 * 64];
    char* const AsB = (char*)As;
    char* const BsB = (char*)Bs;
    const int tid  = threadIdx.x;
    const int lane = tid & 63;
    const int w    = tid >> 6;
    const int lg   = lane >> 4;
    const int lq   = lane & 15;
    const int bm = blockIdx.y * 128;
    const int bn = blockIdx.x * 128;
    const int wr = (w >> 1) * 64;
    const int wc = (w & 1) * 64;
    const int lrow8 = lane >> 3;
    const int gblk  = (lane & 7) ^ lrow8;

    f32x4 acc[4][4];
#pragma unroll
    for (int i = 0; i < 4; ++i)
#pragma unroll
        for (int j = 0; j < 4; ++j) acc[i][j] = (f32x4){0.f, 0.f, 0.f, 0.f};

    for (int k0 = 0; k0 < K; k0 += 64) {
        __syncthreads();
#pragma unroll
        for (int t = 0; t < 4; ++t) {
            const int c = w * 4 + t;
            const int row = c * 8 + lrow8;
            gload16(A + (size_t)(bm + row) * K + k0 + gblk * 8, AsB + c * 1024);
            gload16(Bw + (size_t)(bn + row) * K + k0 + gblk * 8, BsB + c * 1024);
        }
        __syncthreads();

        bf16x8 af[4][2], bfr[4][2];
#pragma unroll
        for (int rt = 0; rt < 4; ++rt) {
            const int row = wr + rt * 16 + lq;
            const int sz = (row & 7) << 4;
            af[rt][0] = *(const bf16x8*)(AsB + row * 128 + ((lg * 16)      ^ sz));
            af[rt][1] = *(const bf16x8*)(AsB + row * 128 + ((64 + lg * 16) ^ sz));
        }
#pragma unroll
        for (int ct = 0; ct < 4; ++ct) {
            const int row = wc + ct * 16 + lq;
            const int sz = (row & 7) << 4;
            bfr[ct][0] = *(const bf16x8*)(BsB + row * 128 + ((lg * 16)      ^ sz));
            bfr[ct][1] = *(const bf16x8*)(BsB + row * 128 + ((64 + lg * 16) ^ sz));
        }
#pragma unroll
        for (int rt = 0; rt < 4; ++rt)
#pragma unroll
            for (int ct = 0; ct < 4; ++ct) {
                acc[rt][ct] = __builtin_amdgcn_mfma_f32_16x16x32_bf16(af[rt][0], bfr[ct][0], acc[rt][ct], 0, 0, 0);
                acc[rt][ct] = __builtin_amdgcn_mfma_f32_16x16x32_bf16(af[rt][1], bfr[ct][1], acc[rt][ct], 0, 0, 0);
            }
    }

#pragma unroll
    for (int rt = 0; rt < 4; ++rt)
#pragma unroll
        for (int ct = 0; ct < 4; ++ct) {
            const int row = bm + wr + rt * 16 + lg * 4;
            const int col = bn + wc + ct * 16 + lq;
            float scale = 1.f;
            if constexpr (QSCALE) scale = ((col % 192) < 64) ? QSCALE_LOG2E : 1.f;
#pragma unroll
            for (int r = 0; r < 4; ++r) {
                float vv = acc[rt][ct][r] * scale;
                if constexpr (OUT_BF16)
                    ((unsigned short*)Cv)[(size_t)(row + r) * N + col] = f2bf(vv);
                else
                    ((float*)Cv)[(size_t)(row + r) * N + col] = vv;
            }
        }
}

// ---------------------------------------------------------------------------
// 64x64 bf16 MFMA GEMM (known-good; output projection)
// ---------------------------------------------------------------------------
template <bool OUT_BF16, bool QSCALE>
__global__ __launch_bounds__(256)
void gemm_bt_mfma(const unsigned short* __restrict__ A,
                  const unsigned short* __restrict__ Bw,
                  void* __restrict__ Cv, int M, int N, int K) {
    __shared__ unsigned short As[64 * 64];
    __shared__ unsigned short Bs[64 * 64];
    char* const AsB = (char*)As;
    char* const BsB = (char*)Bs;
    const int tid  = threadIdx.x;
    const int lane = tid & 63;
    const int w    = tid >> 6;
    const int lg   = lane >> 4;
    const int lq   = lane & 15;
    const int bm = blockIdx.y * 64;
    const int bn = blockIdx.x * 64;
    const int wr = (w >> 1) * 32;
    const int wc = (w & 1) * 32;
    const int sr = tid >> 2;
    const int sc = (tid & 3) * 16;
    const int swzS = (sr & 7) << 4;

    f32x4 acc[2][2];
#pragma unroll
    for (int i = 0; i < 2; ++i)
#pragma unroll
        for (int j = 0; j < 2; ++j) acc[i][j] = (f32x4){0.f, 0.f, 0.f, 0.f};

    const unsigned short* ap = A  + (size_t)(bm + sr) * K + sc;
    const unsigned short* bp = Bw + (size_t)(bn + sr) * K + sc;

    for (int k0 = 0; k0 < K; k0 += 64) {
        __syncthreads();
        u16x8 av0 = *(const u16x8*)(ap + k0);
        u16x8 av1 = *(const u16x8*)(ap + k0 + 8);
        u16x8 bv0 = *(const u16x8*)(bp + k0);
        u16x8 bv1 = *(const u16x8*)(bp + k0 + 8);
        *(u16x8*)(AsB + sr * 128 + ((sc * 2)      ^ swzS)) = av0;
        *(u16x8*)(AsB + sr * 128 + ((sc * 2 + 16) ^ swzS)) = av1;
        *(u16x8*)(BsB + sr * 128 + ((sc * 2)      ^ swzS)) = bv0;
        *(u16x8*)(BsB + sr * 128 + ((sc * 2 + 16) ^ swzS)) = bv1;
        __syncthreads();

        bf16x8 af[2][2], bfr[2][2];
#pragma unroll
        for (int rt = 0; rt < 2; ++rt) {
            const int row = wr + rt * 16 + lq;
            const int sz = (row & 7) << 4;
            af[rt][0] = *(const bf16x8*)(AsB + row * 128 + ((lg * 16)      ^ sz));
            af[rt][1] = *(const bf16x8*)(AsB + row * 128 + ((64 + lg * 16) ^ sz));
        }
#pragma unroll
        for (int ct = 0; ct < 2; ++ct) {
            const int row = wc + ct * 16 + lq;
            const int sz = (row & 7) << 4;
            bfr[ct][0] = *(const bf16x8*)(BsB + row * 128 + ((lg * 16)      ^ sz));
            bfr[ct][1] = *(const bf16x8*)(BsB + row * 128 + ((64 + lg * 16) ^ sz));
        }
#pragma unroll
        for (int rt = 0; rt < 2; ++rt)
#pragma unroll
            for (int ct = 0; ct < 2; ++ct) {
                acc[rt][ct] = __builtin_amdgcn_mfma_f32_16x16x32_bf16(af[rt][0], bfr[ct][0], acc[rt][ct], 0, 0, 0);
                acc[rt][ct] = __builtin_amdgcn_mfma_f32_16x16x32_bf16(af[rt][1], bfr[ct][1], acc[rt][ct], 0, 0, 0);
            }
    }

#pragma unroll
    for (int rt = 0; rt < 2; ++rt)
#pragma unroll
        for (int ct = 0; ct < 2; ++ct) {
            const int row = bm + wr + rt * 16 + lg * 4;
            const int col = bn + wc + ct * 16 + lq;
            float scale = 1.f;
            if constexpr (QSCALE) scale = ((col % 192) < 64) ? QSCALE_LOG2E : 1.f;
#pragma unroll
            for (int r = 0; r < 4; ++r) {
                float vv = acc[rt][ct][r] * scale;
                if constexpr (OUT_BF16)
                    ((unsigned short*)Cv)[(size_t)(row + r) * N + col] = f2bf(vv);
                else
                    ((float*)Cv)[(size_t)(row + r) * N + col] = vv;
            }
        }
}

// ---------------------------------------------------------------------------
// Flash attention v10: BARRIER-FREE main loop. See theory note above.
// ---------------------------------------------------------------------------
__global__ __launch_bounds__(256)
void attn_v10(const unsigned short* __restrict__ qkv, const int* __restrict__ mask,
              unsigned short* __restrict__ vout) {
    __shared__ __align__(16) char pool[32768];     // 4 x 8KB per-wave V^T; merge scratch
    __shared__ __align__(16) float BiasF[S_LEN];
    __shared__ float RsM[2][2][32];

    const int tid  = threadIdx.x;
    const int lane = tid & 63;
    const int w    = tid >> 6;
    const int ln   = lane & 31;
    const int hi   = lane >> 5;
    const int qh   = w >> 1;      // q-half (64 q)
    const int kh   = w & 1;       // key-half (32 keys per 64-key tile)

    // XCD-aware remap: one (b,h)'s 16 q-blocks share an XCD.
    const int d0  = blockIdx.x + 16 * blockIdx.y + 256 * blockIdx.z;
    const int lin = (d0 & 7) * 64 + (d0 >> 3);
    const int q0 = (lin & 15) * 128;
    const int h  = (lin >> 4) & 15;
    const int b  = lin >> 8;
    const unsigned short* const kv =
        qkv + (size_t)b * S_LEN * QKV_LD + (size_t)h * (3 * D_DIM);

    // ---- stage full bias row once (read-only afterwards) ----
    {
        const int4* mr = (const int4*)(mask + (size_t)b * S_LEN);
        int4 m0 = mr[tid * 2];
        int4 m1 = mr[tid * 2 + 1];
        float4 f0 = { m0.x ? 0.f : -30000.f, m0.y ? 0.f : -30000.f,
                      m0.z ? 0.f : -30000.f, m0.w ? 0.f : -30000.f };
        float4 f1 = { m1.x ? 0.f : -30000.f, m1.y ? 0.f : -30000.f,
                      m1.z ? 0.f : -30000.f, m1.w ? 0.f : -30000.f };
        ((float4*)BiasF)[tid * 2]     = f0;
        ((float4*)BiasF)[tid * 2 + 1] = f1;
    }

    // Q B-frags for both q-subtiles (pre-scaled by 0.125*log2e)
    bf16x8 qf[2][4];
#pragma unroll
    for (int qs = 0; qs < 2; ++qs) {
        const unsigned short* qp = kv + (size_t)(q0 + qh * 64 + qs * 32 + ln) * QKV_LD + hi * 8;
#pragma unroll
        for (int kk = 0; kk < 4; ++kk)
            qf[qs][kk] = *(const bf16x8*)(qp + kk * 16);
    }

    __syncthreads();   // BiasF visible; last barrier until the final merge

    const int kgrp = lane & 7;     // -> 4 keys
    const int dgrp = lane >> 3;    // -> 8 d rows
    char* const myV = pool + w * 8192;   // per-wave [64 d][128B], slot-XOR layout

    f32x16 accO[2][2];   // [dt][qs]
#pragma unroll
    for (int dt = 0; dt < 2; ++dt)
#pragma unroll
        for (int qs = 0; qs < 2; ++qs)
#pragma unroll
            for (int r = 0; r < 16; ++r) accO[dt][qs][r] = 0.f;
    f32x4 rsv[2] = {(f32x4){0.f, 0.f, 0.f, 0.f}, (f32x4){0.f, 0.f, 0.f, 0.f}};

    const int NT = S_LEN / 64;   // 32
    for (int it = 0; it < NT; ++it) {
        const int kv0 = it * 64;

        // ---- issue V(t) global loads (own key-half) ----
        u16x8 vr[4];
        {
            const unsigned short* vp = kv + (size_t)(kv0 + kh * 32 + kgrp * 4) * QKV_LD
                                          + 2 * D_DIM + dgrp * 8;
#pragma unroll
            for (int i = 0; i < 4; ++i)
                vr[i] = *(const u16x8*)(vp + (size_t)i * QKV_LD);
        }

        // ---- K A-frags direct from global (own key-half) ----
        bf16x8 kf[4];
        {
            const unsigned short* kp = kv + (size_t)(kv0 + kh * 32 + ln) * QKV_LD
                                          + D_DIM + hi * 8;
#pragma unroll
            for (int kk = 0; kk < 4; ++kk)
                kf[kk] = *(const bf16x8*)(kp + kk * 16);
        }

        // ---- bias (shared by both q-subtiles) + S init ----
        f32x16 s[2];
#pragma unroll
        for (int m = 0; m < 4; ++m) {
            f32x4 b4 = *(const f32x4*)(&BiasF[kv0 + kh * 32 + m * 8 + hi * 4]);
#pragma unroll
            for (int i = 0; i < 4; ++i) { s[0][m * 4 + i] = b4[i]; s[1][m * 4 + i] = b4[i]; }
        }

        // ---- S^T = K Q^T (log2 domain) ----
        __builtin_amdgcn_s_setprio(1);
#pragma unroll
        for (int kk = 0; kk < 4; ++kk) {
            s[0] = __builtin_amdgcn_mfma_f32_32x32x16_bf16(kf[kk], qf[0][kk], s[0], 0, 0, 0);
            s[1] = __builtin_amdgcn_mfma_f32_32x32x16_bf16(kf[kk], qf[1][kk], s[1], 0, 0, 0);
        }
        __builtin_amdgcn_s_setprio(0);

        // ---- p = exp2(s); per-qs row-sum accumulators ----
#pragma unroll
        for (int qs = 0; qs < 2; ++qs)
#pragma unroll
            for (int r = 0; r < 16; ++r) {
                float p = __builtin_amdgcn_exp2f(s[qs][r]);
                s[qs][r] = p;
                rsv[qs][r & 3] += p;
            }

        // ---- assemble P^T B-frags in-register (per q-subtile) ----
        bf16x8 pb[2][2];
#pragma unroll
        for (int qs = 0; qs < 2; ++qs) {
            unsigned wA[4], wB[4];
#pragma unroll
            for (int m = 0; m < 4; ++m) {
                wA[m] = cvtpk_bf16(s[qs][4 * m + 0], s[qs][4 * m + 1]);
                wB[m] = cvtpk_bf16(s[qs][4 * m + 2], s[qs][4 * m + 3]);
            }
#pragma unroll
            for (int t = 0; t < 2; ++t) {
                i32x2 ra = __builtin_amdgcn_permlane32_swap((int)wA[2 * t], (int)wA[2 * t + 1], false, false);
                i32x2 rb = __builtin_amdgcn_permlane32_swap((int)wB[2 * t], (int)wB[2 * t + 1], false, false);
                union { unsigned u[4]; bf16x8 v; } uu;
                uu.u[0] = (unsigned)ra[0];
                uu.u[1] = (unsigned)rb[0];
                uu.u[2] = (unsigned)ra[1];
                uu.u[3] = (unsigned)rb[1];
                pb[qs][t] = uu.v;
            }
        }

        // ---- V(t) regs -> private LDS (transposed, slot-XOR layout);
        //      single buffer safe: same-wave DS ops execute in order ----
#pragma unroll
        for (int j = 0; j < 8; ++j) {
            u16x4 o = { vr[0][j], vr[1][j], vr[2][j], vr[3][j] };
            const int row = dgrp * 8 + j;
            *(u16x4*)(myV + row * 128
                      + ((((kgrp >> 1) ^ (row & 7)) << 4) + ((kgrp & 1) * 8))) = o;
        }

        // ---- O^T += V^T P^T (reads own private region) ----
        __builtin_amdgcn_s_setprio(1);
#pragma unroll
        for (int dt = 0; dt < 2; ++dt) {
            const int drow = dt * 32 + ln;
#pragma unroll
            for (int t = 0; t < 2; ++t) {
                const int c = t * 2 + hi;   // local 16B col slot (0..3)
                bf16x8 va = *(const bf16x8*)(myV + drow * 128 + ((c ^ (drow & 7)) << 4));
                accO[dt][0] = __builtin_amdgcn_mfma_f32_32x32x16_bf16(va, pb[0][t], accO[dt][0], 0, 0, 0);
                accO[dt][1] = __builtin_amdgcn_mfma_f32_32x32x16_bf16(va, pb[1][t], accO[dt][1], 0, 0, 0);
            }
        }
        __builtin_amdgcn_s_setprio(0);
    }

    // ---- per-wave row-sum: in-lane + hi-partner reduce ----
    float rs[2];
#pragma unroll
    for (int qs = 0; qs < 2; ++qs) {
        float t = rsv[qs][0] + rsv[qs][1] + rsv[qs][2] + rsv[qs][3];
        i32x2 rr = __builtin_amdgcn_permlane32_swap(__float_as_int(t), __float_as_int(t), false, false);
        rs[qs] = __int_as_float(rr[0]) + __int_as_float(rr[1]);
    }

    // ---- merge key-half partials across wave pairs (exact addition) ----
    __syncthreads();                      // all private-V use done; pool free
    const int lswz = (lane & 7) << 4;
    if (kh == 1) {                        // odd waves: publish partials
        char* const reg = pool + qh * 16384;
#pragma unroll
        for (int qs = 0; qs < 2; ++qs) {
#pragma unroll
            for (int dt = 0; dt < 2; ++dt)
#pragma unroll
                for (int r4 = 0; r4 < 4; ++r4) {
                    f32x4 v = { accO[dt][qs][4 * r4 + 0], accO[dt][qs][4 * r4 + 1],
                                accO[dt][qs][4 * r4 + 2], accO[dt][qs][4 * r4 + 3] };
                    *(f32x4*)(reg + lane * 256 + ((qs * 128 + dt * 64 + r4 * 16) ^ lswz)) = v;
                }
            if (hi == 0) RsM[qh][qs][ln] = rs[qs];
        }
    }
    __syncthreads();
    if (kh == 0) {                        // even waves: combine + store
        const char* const reg = pool + qh * 16384;
#pragma unroll
        for (int qs = 0; qs < 2; ++qs) {
            const float inv = 1.f / (rs[qs] + RsM[qh][qs][ln]);
            unsigned short* op = vout +
                (size_t)(b * S_LEN + q0 + qh * 64 + qs * 32 + ln) * E_DIM + h * D_DIM;
#pragma unroll
            for (int dt = 0; dt < 2; ++dt)
#pragma unroll
                for (int m = 0; m < 4; ++m) {
                    f32x4 part = *(const f32x4*)(reg + lane * 256 + ((qs * 128 + dt * 64 + m * 16) ^ lswz));
                    u16x4 o;
#pragma unroll
                    for (int i = 0; i < 4; ++i)
                        o[i] = f2bf((accO[dt][qs][4 * m + i] + part[i]) * inv);
                    *(u16x4*)(op + dt * 32 + m * 8 + hi * 4) = o;
                }
        }
    }
}

// ---------------------------------------------------------------------------
extern "C" void kernel_launch(void* const* d_in, const int* in_sizes, int n_in,
                              void* d_out, int out_size, void* d_ws, size_t ws_size,
                              hipStream_t stream) {
    const float* x      = (const float*)d_in[0];
    const int*   mask   = (const int*)d_in[1];
    const float* w_qkv  = (const float*)d_in[2];
    const float* w_o    = (const float*)d_in[3];
    float*       out    = (float*)d_out;

    const int M = B_NUM * S_LEN;     // 4096
    unsigned short* qkvb = (unsigned short*)d_ws;                    // M x 3E
    unsigned short* vbuf = qkvb + (size_t)M * 3 * E_DIM;             // M x E
    unsigned short* xb   = vbuf + (size_t)M * E_DIM;                 // M x E
    unsigned short* wqb  = xb   + (size_t)M * E_DIM;                 // 3E x E
    unsigned short* wob  = wqb  + (size_t)3 * E_DIM * E_DIM;         // E x E

    dim3 blk(256);
    {
        int n4;
        n4 = M * E_DIM / 4;
        cvt_f32_bf16<<<dim3((n4 + 255) / 256), blk, 0, stream>>>(x, xb, n4);
        n4 = 3 * E_DIM * E_DIM / 4;
        cvt_f32_bf16<<<dim3((n4 + 255) / 256), blk, 0, stream>>>(w_qkv, wqb, n4);
        n4 = E_DIM * E_DIM / 4;
        cvt_f32_bf16<<<dim3((n4 + 255) / 256), blk, 0, stream>>>(w_o, wob, n4);
    }

    // QKV projection (q columns pre-scaled by 0.125*log2e), bf16 out
    gemm_bt_mfma128<true, true><<<dim3(3 * E_DIM / 128, M / 128), blk, 0, stream>>>(
        xb, wqb, qkvb, M, 3 * E_DIM, E_DIM);

    // flash attention v10 (barrier-free main loop)
    attn_v10<<<dim3(S_LEN / 128, H_NUM, B_NUM), blk, 0, stream>>>(qkvb, mask, vbuf);

    // output projection, fp32 out
    gemm_bt_mfma<false, false><<<dim3(E_DIM / 64, M / 64), blk, 0, stream>>>(
        vbuf, wob, out, M, E_DIM, E_DIM);
}